// Round 1
// baseline (360.350 us; speedup 1.0000x reference)
//
#include <hip/hip_runtime.h>

// ---------------------------------------------------------------------------
// HVIN: maxpool -> composite5x5 conv -> VI scan (32^2) -> upsample ->
//       composite5x5 conv -> VI scan (64^2) -> final conv + BN + dueling head
//
// ws float layout:
//   [0..49]     WeffO  (outer composite 5x5, 2 in-ch)
//   [64..225]   GO     (outer border-correction tensors, [by][bx][i][ay][ax])
//   [256..305]  WeffI  (inner composite)
//   [320..481]  GI     (inner border-correction)
//   [512..521]  bn_sum[10]
//   [528..537]  bn_sumsq[10]
//   [544..1823] q_pix[128][10]  (raw q at (S1,S2) before BN)
// ---------------------------------------------------------------------------

#define NEG_BIG (-3.402823466e38f)

__global__ void k_precomp(const float* __restrict__ conv_h_w,
                          const float* __restrict__ conv_r_w,
                          const float* __restrict__ vi_h_w,
                          const float* __restrict__ vi_r_w,
                          float* __restrict__ ws) {
    __shared__ float sG[2][162];
    int t = threadIdx.x; // 512 threads
    if (t < 324) {
        int set = t / 162;      // 0 = outer, 1 = inner
        int e   = t % 162;
        int ax = e % 3;  int e1 = e / 3;
        int ay = e1 % 3; int e2 = e1 / 3;
        int i  = e2 % 2; int e3 = e2 / 2;
        int bx = e3 % 3; int by = e3 / 3;
        const float* Wh = set ? vi_h_w : conv_h_w;
        const float* Wr = set ? vi_r_w : conv_r_w;
        float acc = 0.f;
        for (int c = 0; c < 150; ++c)
            acc += Wr[(c*3+by)*3+bx] * Wh[((c*2+i)*3+ay)*3+ax];
        sG[set][e] = acc;
        ws[(set ? 320 : 64) + e] = acc;
    }
    if (t >= 480 && t < 512) ws[512 + (t - 480)] = 0.f;  // zero BN accumulators
    __syncthreads();
    if (t < 100) {
        int set = t / 50;
        int e   = t % 50;
        int i  = e / 25;
        int oy = (e % 25) / 5;
        int ox = e % 5;
        float acc = 0.f;
        for (int by = 0; by < 3; ++by) {
            int ay = oy - by; if (ay < 0 || ay > 2) continue;
            for (int bx = 0; bx < 3; ++bx) {
                int ax = ox - bx; if (ax < 0 || ax > 2) continue;
                acc += sG[set][(((by*3+bx)*2+i)*3+ay)*3+ax];
            }
        }
        ws[(set ? 256 : 0) + e] = acc;
    }
}

__global__ __launch_bounds__(512) void k_main(
    const float* __restrict__ Xg,        // [128][2][64][64]
    const int*   __restrict__ S1,
    const int*   __restrict__ S2,
    const float* __restrict__ conv_q_ws, // [16][10][3][3][3]
    const float* __restrict__ vi_q_ws,   // [16][10][2][3][3]
    const float* __restrict__ ws,        // composites (read-only here)
    float*       __restrict__ wsm)       // BN accum + q_pix
{
    __shared__ float sX[2][64][64];
    __shared__ float sX1[2][32][32];
    __shared__ float sr1[32][32];        // r1, later reused as v1
    __shared__ float sva[32][32];
    __shared__ float svb[32][32];
    __shared__ float sm[64][64];
    __shared__ float sr[64][64];
    __shared__ float sV[2][64][64];

    const int n = blockIdx.x;
    const int t = threadIdx.x;

    // ---- P0: load X image into LDS (coalesced float4) ----
    {
        const float4* src = (const float4*)(Xg + (size_t)n * 2 * 4096);
        float4* dst = (float4*)&sX[0][0][0];
        for (int idx = t; idx < 2048; idx += 512) dst[idx] = src[idx];
    }
    __syncthreads();

    // ---- P1: maxpool 2x2 -> sX1 ----
    for (int idx = t; idx < 2048; idx += 512) {
        int c = idx >> 10;
        int y = (idx >> 5) & 31;
        int x = idx & 31;
        float a0 = sX[c][2*y][2*x],   a1 = sX[c][2*y][2*x+1];
        float a2 = sX[c][2*y+1][2*x], a3 = sX[c][2*y+1][2*x+1];
        sX1[c][y][x] = fmaxf(fmaxf(a0, a1), fmaxf(a2, a3));
    }
    __syncthreads();

    // ---- P2: r1 = composite 5x5 conv(X1) + border correction ----
    {
        const float* WeffI = ws + 256;
        const float* GI    = ws + 320;
        int y  = t >> 4;
        int x0 = (t & 15) * 2;
        for (int dxp = 0; dxp < 2; ++dxp) {
            int x = x0 + dxp;
            float acc = 0.f;
            for (int i = 0; i < 2; ++i)
                for (int oy = 0; oy < 5; ++oy) {
                    int yy = y + oy - 2; if (yy < 0 || yy >= 32) continue;
                    for (int ox = 0; ox < 5; ++ox) {
                        int xx = x + ox - 2; if (xx < 0 || xx >= 32) continue;
                        acc += WeffI[i*25 + oy*5 + ox] * sX1[i][yy][xx];
                    }
                }
            if (y == 0 || y == 31 || x == 0 || x == 31) {
                float corr = 0.f;
                for (int by = 0; by < 3; ++by)
                    for (int bx = 0; bx < 3; ++bx) {
                        int qy = y + by - 1, qx = x + bx - 1;
                        if (qy >= 0 && qy < 32 && qx >= 0 && qx < 32) continue;
                        const float* Gb = GI + (by*3+bx)*18;
                        for (int i = 0; i < 2; ++i)
                            for (int ay = 0; ay < 3; ++ay) {
                                int yy2 = qy + ay - 1; if (yy2 < 0 || yy2 >= 32) continue;
                                for (int ax = 0; ax < 3; ++ax) {
                                    int xx2 = qx + ax - 1; if (xx2 < 0 || xx2 >= 32) continue;
                                    corr += Gb[i*9 + ay*3 + ax] * sX1[i][yy2][xx2];
                                }
                            }
                    }
                acc -= corr;
            }
            sr1[y][x] = acc;
        }
        sva[y][x0] = 0.f;
        sva[y][x0 + 1] = 0.f;
    }
    __syncthreads();

    // ---- P3: inner VI loop (16 steps, 32x32, in-ch {r1, v}) ----
    {
        int y  = t >> 4;
        int x0 = (t & 15) * 2;
        float s0 = 0.f, s1a = 0.f;
        float (*vcur)[32] = sva;
        float (*vnxt)[32] = svb;
        for (int k = 0; k < 16; ++k) {
            const float* wk = vi_q_ws + k * 180;
            float pr[3][4], pv[3][4];
            #pragma unroll
            for (int dy = 0; dy < 3; ++dy)
                #pragma unroll
                for (int dx = 0; dx < 4; ++dx) {
                    int yy = y + dy - 1, xx = x0 + dx - 1;
                    bool in = (yy >= 0 && yy < 32 && xx >= 0 && xx < 32);
                    pr[dy][dx] = in ? sr1[yy][xx]  : 0.f;
                    pv[dy][dx] = in ? vcur[yy][xx] : 0.f;
                }
            float m0 = NEG_BIG, m1 = NEG_BIG;
            for (int c = 0; c < 10; ++c) {
                const float* wc = wk + c * 18;
                float q0 = 0.f, q1 = 0.f;
                #pragma unroll
                for (int ky = 0; ky < 3; ++ky)
                    #pragma unroll
                    for (int kx = 0; kx < 3; ++kx) {
                        float wr = wc[ky*3+kx];
                        float wv = wc[9 + ky*3+kx];
                        q0 += wr * pr[ky][kx]   + wv * pv[ky][kx];
                        q1 += wr * pr[ky][kx+1] + wv * pv[ky][kx+1];
                    }
                m0 = fmaxf(m0, q0);
                m1 = fmaxf(m1, q1);
            }
            vnxt[y][x0] = m0;
            vnxt[y][x0+1] = m1;
            s0 += m0;
            s1a += m1;
            __syncthreads();
            float (*tmp)[32] = vcur; vcur = vnxt; vnxt = tmp;
        }
        // v1 = s/4 -> reuse sr1
        sr1[y][x0]   = s0  * 0.25f;
        sr1[y][x0+1] = s1a * 0.25f;
    }
    __syncthreads();

    // ---- P4: m = bilinear upsample(v1) 32->64 (half-pixel, edge-clamped) ----
    {
        int ty = t >> 5, tx = t & 31;
        int r0 = ty * 4, c0 = tx * 2;
        #pragma unroll
        for (int dy = 0; dy < 4; ++dy) {
            int Y = r0 + dy;
            int y0, y1; float wy0, wy1;
            if ((Y & 1) == 0) { y1 = Y >> 1; y0 = (y1 > 0) ? y1 - 1 : 0; wy1 = 0.75f; wy0 = 0.25f; }
            else              { y0 = Y >> 1; y1 = (y0 < 31) ? y0 + 1 : 31; wy0 = 0.75f; wy1 = 0.25f; }
            #pragma unroll
            for (int dx = 0; dx < 2; ++dx) {
                int Xc = c0 + dx;
                int xa, xb; float wx0, wx1;
                if ((Xc & 1) == 0) { xb = Xc >> 1; xa = (xb > 0) ? xb - 1 : 0; wx1 = 0.75f; wx0 = 0.25f; }
                else               { xa = Xc >> 1; xb = (xa < 31) ? xa + 1 : 31; wx0 = 0.75f; wx1 = 0.25f; }
                sm[Y][Xc] = wy0 * (wx0 * sr1[y0][xa] + wx1 * sr1[y0][xb])
                          + wy1 * (wx0 * sr1[y1][xa] + wx1 * sr1[y1][xb]);
            }
        }
    }

    // ---- P5: r = composite 5x5 conv(X) + border correction ----
    {
        const float* WeffO = ws;
        const float* GO    = ws + 64;
        int ty = t >> 5, tx = t & 31;
        int r0 = ty * 4, c0 = tx * 2;
        for (int dy = 0; dy < 4; ++dy)
            for (int dx = 0; dx < 2; ++dx) {
                int y = r0 + dy, x = c0 + dx;
                float acc = 0.f;
                for (int i = 0; i < 2; ++i)
                    for (int oy = 0; oy < 5; ++oy) {
                        int yy = y + oy - 2; if (yy < 0 || yy >= 64) continue;
                        for (int ox = 0; ox < 5; ++ox) {
                            int xx = x + ox - 2; if (xx < 0 || xx >= 64) continue;
                            acc += WeffO[i*25 + oy*5 + ox] * sX[i][yy][xx];
                        }
                    }
                if (y == 0 || y == 63 || x == 0 || x == 63) {
                    float corr = 0.f;
                    for (int by = 0; by < 3; ++by)
                        for (int bx = 0; bx < 3; ++bx) {
                            int qy = y + by - 1, qx = x + bx - 1;
                            if (qy >= 0 && qy < 64 && qx >= 0 && qx < 64) continue;
                            const float* Gb = GO + (by*3+bx)*18;
                            for (int i = 0; i < 2; ++i)
                                for (int ay = 0; ay < 3; ++ay) {
                                    int yy2 = qy + ay - 1; if (yy2 < 0 || yy2 >= 64) continue;
                                    for (int ax = 0; ax < 3; ++ax) {
                                        int xx2 = qx + ax - 1; if (xx2 < 0 || xx2 >= 64) continue;
                                        corr += Gb[i*9 + ay*3 + ax] * sX[i][yy2][xx2];
                                    }
                                }
                        }
                    acc -= corr;
                }
                sr[y][x] = acc;
            }
        for (int idx = t; idx < 4096; idx += 512) (&sV[0][0][0])[idx] = 0.f;
    }
    __syncthreads();

    // ---- P6: outer VI loop (16 steps, 64x64, in-ch {m, r, v}) + P7 final ----
    {
        int ty = t >> 5, tx = t & 31;
        int r0 = ty * 4, c0 = tx * 2;

        // step-invariant patches of m and r (6x4 with zero-pad halo)
        float pm[6][4], prr[6][4];
        #pragma unroll
        for (int dy = 0; dy < 6; ++dy)
            #pragma unroll
            for (int dx = 0; dx < 4; ++dx) {
                int yy = r0 + dy - 1, xx = c0 + dx - 1;
                bool in = (yy >= 0 && yy < 64 && xx >= 0 && xx < 64);
                pm[dy][dx]  = in ? sm[yy][xx] : 0.f;
                prr[dy][dx] = in ? sr[yy][xx] : 0.f;
            }

        float sacc[8];
        #pragma unroll
        for (int j = 0; j < 8; ++j) sacc[j] = 0.f;

        int cur = 0;
        for (int k = 0; k < 16; ++k) {
            const float* wk = conv_q_ws + k * 270;
            float pv[6][4];
            #pragma unroll
            for (int dy = 0; dy < 6; ++dy)
                #pragma unroll
                for (int dx = 0; dx < 4; ++dx) {
                    int yy = r0 + dy - 1, xx = c0 + dx - 1;
                    bool in = (yy >= 0 && yy < 64 && xx >= 0 && xx < 64);
                    pv[dy][dx] = in ? sV[cur][yy][xx] : 0.f;
                }
            float vmax[8];
            #pragma unroll
            for (int j = 0; j < 8; ++j) vmax[j] = NEG_BIG;
            for (int c = 0; c < 10; ++c) {
                const float* wc = wk + c * 27;
                float q[8];
                #pragma unroll
                for (int j = 0; j < 8; ++j) q[j] = 0.f;
                #pragma unroll
                for (int ky = 0; ky < 3; ++ky)
                    #pragma unroll
                    for (int kx = 0; kx < 3; ++kx) {
                        float wm = wc[ky*3+kx];
                        float wr = wc[9  + ky*3+kx];
                        float wv = wc[18 + ky*3+kx];
                        #pragma unroll
                        for (int dy = 0; dy < 4; ++dy)
                            #pragma unroll
                            for (int dx = 0; dx < 2; ++dx)
                                q[dy*2+dx] += wm * pm[ky+dy][kx+dx]
                                            + wr * prr[ky+dy][kx+dx]
                                            + wv * pv[ky+dy][kx+dx];
                    }
                #pragma unroll
                for (int j = 0; j < 8; ++j) vmax[j] = fmaxf(vmax[j], q[j]);
            }
            #pragma unroll
            for (int dy = 0; dy < 4; ++dy)
                #pragma unroll
                for (int dx = 0; dx < 2; ++dx) {
                    sV[cur ^ 1][r0+dy][c0+dx] = vmax[dy*2+dx];
                    sacc[dy*2+dx] += vmax[dy*2+dx];
                }
            __syncthreads();
            cur ^= 1;
        }

        // vbar = s/16 into sV[0]
        #pragma unroll
        for (int dy = 0; dy < 4; ++dy)
            #pragma unroll
            for (int dx = 0; dx < 2; ++dx)
                sV[0][r0+dy][c0+dx] = sacc[dy*2+dx] * (1.f / 16.f);
        __syncthreads();

        // ---- P7: final conv (w15) + BN stats + (S1,S2) selection ----
        const float* wk = conv_q_ws + 15 * 270;
        float pv[6][4];
        #pragma unroll
        for (int dy = 0; dy < 6; ++dy)
            #pragma unroll
            for (int dx = 0; dx < 4; ++dx) {
                int yy = r0 + dy - 1, xx = c0 + dx - 1;
                bool in = (yy >= 0 && yy < 64 && xx >= 0 && xx < 64);
                pv[dy][dx] = in ? sV[0][yy][xx] : 0.f;
            }
        int sel_y = S1[n], sel_x = S2[n];
        float* qpix = wsm + 544 + n * 10;
        for (int c = 0; c < 10; ++c) {
            const float* wc = wk + c * 27;
            float q[8];
            #pragma unroll
            for (int j = 0; j < 8; ++j) q[j] = 0.f;
            #pragma unroll
            for (int ky = 0; ky < 3; ++ky)
                #pragma unroll
                for (int kx = 0; kx < 3; ++kx) {
                    float wm = wc[ky*3+kx];
                    float wr = wc[9  + ky*3+kx];
                    float wv = wc[18 + ky*3+kx];
                    #pragma unroll
                    for (int dy = 0; dy < 4; ++dy)
                        #pragma unroll
                        for (int dx = 0; dx < 2; ++dx)
                            q[dy*2+dx] += wm * pm[ky+dy][kx+dx]
                                        + wr * prr[ky+dy][kx+dx]
                                        + wv * pv[ky+dy][kx+dx];
                }
            float ls = 0.f, lq = 0.f;
            #pragma unroll
            for (int dy = 0; dy < 4; ++dy)
                #pragma unroll
                for (int dx = 0; dx < 2; ++dx) {
                    float v = q[dy*2+dx];
                    ls += v; lq += v * v;
                    if (r0 + dy == sel_y && c0 + dx == sel_x) qpix[c] = v;
                }
            #pragma unroll
            for (int off = 32; off > 0; off >>= 1) {
                ls += __shfl_down(ls, off);
                lq += __shfl_down(lq, off);
            }
            if ((t & 63) == 0) {
                atomicAdd(wsm + 512 + c, ls);
                atomicAdd(wsm + 528 + c, lq);
            }
        }
    }
}

__global__ void k_final(const float* __restrict__ ws,
                        const float* __restrict__ gamma,
                        const float* __restrict__ beta,
                        const float* __restrict__ w1,
                        const float* __restrict__ w2,
                        float* __restrict__ out) {
    int n = threadIdx.x;
    if (n >= 128) return;
    const float inv = 1.f / 524288.f;
    float qn[10];
    for (int c = 0; c < 10; ++c) {
        float mean = ws[512 + c] * inv;
        float var  = ws[528 + c] * inv - mean * mean;
        float q    = ws[544 + n * 10 + c];
        qn[c] = (q - mean) * rsqrtf(var + 1e-5f) * gamma[c] + beta[c];
    }
    float a = 0.f;
    for (int c = 0; c < 10; ++c) a += qn[c] * w1[c];
    a = fmaxf(a, 0.f);
    float b[8], mb = 0.f;
    for (int j = 0; j < 8; ++j) {
        float bj = 0.f;
        for (int c = 0; c < 10; ++c) bj += qn[c] * w2[j * 10 + c];
        bj = fmaxf(bj, 0.f);
        b[j] = bj;
        mb += bj;
    }
    mb *= 0.125f;
    for (int j = 0; j < 8; ++j) out[n * 8 + j] = a + b[j] - mb;
}

extern "C" void kernel_launch(void* const* d_in, const int* in_sizes, int n_in,
                              void* d_out, int out_size, void* d_ws, size_t ws_size,
                              hipStream_t stream) {
    const float* X         = (const float*)d_in[0];
    const int*   S1        = (const int*)  d_in[1];
    const int*   S2        = (const int*)  d_in[2];
    const float* conv_h_w  = (const float*)d_in[3];
    const float* conv_r_w  = (const float*)d_in[4];
    const float* conv_q_ws = (const float*)d_in[5];
    const float* bn_gamma  = (const float*)d_in[6];
    const float* bn_beta   = (const float*)d_in[7];
    const float* duel_w1   = (const float*)d_in[8];
    const float* duel_w2   = (const float*)d_in[9];
    const float* vi_h_w    = (const float*)d_in[10];
    const float* vi_r_w    = (const float*)d_in[11];
    const float* vi_q_ws   = (const float*)d_in[12];
    float* ws = (float*)d_ws;

    k_precomp<<<1, 512, 0, stream>>>(conv_h_w, conv_r_w, vi_h_w, vi_r_w, ws);
    k_main<<<128, 512, 0, stream>>>(X, S1, S2, conv_q_ws, vi_q_ws, ws, ws);
    k_final<<<1, 128, 0, stream>>>(ws, bn_gamma, bn_beta, duel_w1, duel_w2, (float*)d_out);
}

// Round 2
// 252.358 us; speedup vs baseline: 1.4279x; 1.4279x over previous
//
#include <hip/hip_runtime.h>

// ---------------------------------------------------------------------------
// HVIN: maxpool -> composite5x5 conv -> VI scan (32^2, redundant per pair) ->
//       upsample -> composite5x5 conv -> VI scan (64^2, split across a block
//       pair with per-step halo exchange) -> final conv + BN + dueling head
//
// Grid: 256 blocks x 1024 threads. Blocks (2n, 2n+1) handle image n rows
// [0,32) and [32,64). Pair-sync via device-scope atomics in d_ws.
//
// ws float layout:
//   [0..49]     WeffO   [64..225]  GO    [256..305] WeffI   [320..481] GI
//   [512..521]  bn_sum  [528..537] bn_sumsq
//   [544..1823] q_pix[128][10]
//   ints [1824..2079]: flags[256]  (zeroed by k_precomp each launch)
//   [2176..]    halo[256 blocks][2 slots][64]
// ---------------------------------------------------------------------------

#define NEG_BIG (-3.402823466e38f)
#define SCOPE_AGENT __HIP_MEMORY_SCOPE_AGENT

__global__ void k_precomp(const float* __restrict__ conv_h_w,
                          const float* __restrict__ conv_r_w,
                          const float* __restrict__ vi_h_w,
                          const float* __restrict__ vi_r_w,
                          float* __restrict__ ws) {
    __shared__ float sG[2][162];
    int t = threadIdx.x; // 512 threads
    if (t < 324) {
        int set = t / 162;      // 0 = outer, 1 = inner
        int e   = t % 162;
        int ax = e % 3;  int e1 = e / 3;
        int ay = e1 % 3; int e2 = e1 / 3;
        int i  = e2 % 2; int e3 = e2 / 2;
        int bx = e3 % 3; int by = e3 / 3;
        const float* Wh = set ? vi_h_w : conv_h_w;
        const float* Wr = set ? vi_r_w : conv_r_w;
        float acc = 0.f;
        for (int c = 0; c < 150; ++c)
            acc += Wr[(c*3+by)*3+bx] * Wh[((c*2+i)*3+ay)*3+ax];
        sG[set][e] = acc;
        ws[(set ? 320 : 64) + e] = acc;
    }
    if (t >= 480 && t < 512) ws[512 + (t - 480)] = 0.f;  // zero BN accumulators
    if (t < 256) ((int*)ws)[1824 + t] = 0;               // zero pair-sync flags
    __syncthreads();
    if (t < 100) {
        int set = t / 50;
        int e   = t % 50;
        int i  = e / 25;
        int oy = (e % 25) / 5;
        int ox = e % 5;
        float acc = 0.f;
        for (int by = 0; by < 3; ++by) {
            int ay = oy - by; if (ay < 0 || ay > 2) continue;
            for (int bx = 0; bx < 3; ++bx) {
                int ax = ox - bx; if (ax < 0 || ax > 2) continue;
                acc += sG[set][(((by*3+bx)*2+i)*3+ay)*3+ax];
            }
        }
        ws[(set ? 256 : 0) + e] = acc;
    }
}

__global__ __launch_bounds__(1024) void k_main(
    const float* __restrict__ Xg,        // [128][2][64][64]
    const int*   __restrict__ S1,
    const int*   __restrict__ S2,
    const float* __restrict__ conv_q_ws, // [16][10][3][3][3]
    const float* __restrict__ vi_q_ws,   // [16][10][2][3][3]
    const float* __restrict__ ws,        // composites (read-only)
    float*       __restrict__ wsm)       // BN accum + qpix + flags + halo
{
    __shared__ float sX[2][64][64];      // full image (both halves need halo)
    __shared__ float sX1[2][32][32];
    __shared__ float sr1[34][34];        // ring-padded r1, later v1
    __shared__ float sva[34][34];
    __shared__ float svb[34][34];
    __shared__ float sm[34][66];         // rows: global gr0-1..gr0+32, ring-padded
    __shared__ float sr[34][66];
    __shared__ float sV[2][34][66];
    __shared__ float sRed[10][2];

    const int bid  = blockIdx.x;
    const int n    = bid >> 1;
    const int half = bid & 1;
    const int gr0  = half << 5;          // first own global row
    const int t    = threadIdx.x;

    int*   flagMine = (int*)wsm + 1824 + bid;
    int*   flagPart = (int*)wsm + 1824 + (bid ^ 1);
    float* ghMine   = wsm + 2176 + bid * 128;
    float* ghPart   = wsm + 2176 + (bid ^ 1) * 128;

    // ---- zero-init ring/halo arrays (rings are never written again) ----
    {
        float* z;
        z = &sr1[0][0];   for (int i = t; i < 1156; i += 1024) z[i] = 0.f;
        z = &sva[0][0];   for (int i = t; i < 1156; i += 1024) z[i] = 0.f;
        z = &svb[0][0];   for (int i = t; i < 1156; i += 1024) z[i] = 0.f;
        z = &sm[0][0];    for (int i = t; i < 2244; i += 1024) z[i] = 0.f;
        z = &sr[0][0];    for (int i = t; i < 2244; i += 1024) z[i] = 0.f;
        z = &sV[0][0][0]; for (int i = t; i < 4488; i += 1024) z[i] = 0.f;
    }
    // ---- P0: load full X (coalesced float4) ----
    {
        const float4* src = (const float4*)(Xg + (size_t)n * 8192);
        float4* dst = (float4*)&sX[0][0][0];
        dst[t] = src[t];
        dst[t + 1024] = src[t + 1024];
    }
    __syncthreads();

    // ---- P1: maxpool 2x2 -> sX1 ----
    for (int idx = t; idx < 2048; idx += 1024) {
        int c = idx >> 10;
        int y = (idx >> 5) & 31;
        int x = idx & 31;
        float a0 = sX[c][2*y][2*x],   a1 = sX[c][2*y][2*x+1];
        float a2 = sX[c][2*y+1][2*x], a3 = sX[c][2*y+1][2*x+1];
        sX1[c][y][x] = fmaxf(fmaxf(a0, a1), fmaxf(a2, a3));
    }
    __syncthreads();

    // ---- P2: r1 = composite 5x5 conv(X1) + border correction (redundant) ----
    {
        const float* WeffI = ws + 256;
        const float* GI    = ws + 320;
        int y = t >> 5, x = t & 31;
        float acc = 0.f;
        for (int i = 0; i < 2; ++i)
            for (int oy = 0; oy < 5; ++oy) {
                int yy = y + oy - 2; if (yy < 0 || yy >= 32) continue;
                for (int ox = 0; ox < 5; ++ox) {
                    int xx = x + ox - 2; if (xx < 0 || xx >= 32) continue;
                    acc += WeffI[i*25 + oy*5 + ox] * sX1[i][yy][xx];
                }
            }
        if (y == 0 || y == 31 || x == 0 || x == 31) {
            float corr = 0.f;
            for (int by = 0; by < 3; ++by)
                for (int bx = 0; bx < 3; ++bx) {
                    int qy = y + by - 1, qx = x + bx - 1;
                    if (qy >= 0 && qy < 32 && qx >= 0 && qx < 32) continue;
                    const float* Gb = GI + (by*3+bx)*18;
                    for (int i = 0; i < 2; ++i)
                        for (int ay = 0; ay < 3; ++ay) {
                            int yy2 = qy + ay - 1; if (yy2 < 0 || yy2 >= 32) continue;
                            for (int ax = 0; ax < 3; ++ax) {
                                int xx2 = qx + ax - 1; if (xx2 < 0 || xx2 >= 32) continue;
                                corr += Gb[i*9 + ay*3 + ax] * sX1[i][yy2][xx2];
                            }
                        }
                }
            acc -= corr;
        }
        sr1[1+y][1+x] = acc;
    }
    __syncthreads();

    // ---- P3: inner VI loop (16 steps, 32x32, redundant per pair) ----
    {
        int y = t >> 5, x = t & 31;
        float pr[3][3];
        #pragma unroll
        for (int dy = 0; dy < 3; ++dy)
            #pragma unroll
            for (int dx = 0; dx < 3; ++dx)
                pr[dy][dx] = sr1[y+dy][x+dx];
        float s = 0.f;
        float (*vc)[34] = sva;
        float (*vn)[34] = svb;
        for (int k = 0; k < 16; ++k) {
            const float* wk = vi_q_ws + k * 180;
            float pv[3][3];
            #pragma unroll
            for (int dy = 0; dy < 3; ++dy)
                #pragma unroll
                for (int dx = 0; dx < 3; ++dx)
                    pv[dy][dx] = vc[y+dy][x+dx];
            float m = NEG_BIG;
            for (int c = 0; c < 10; ++c) {
                const float* wc = wk + c * 18;
                float q = 0.f;
                #pragma unroll
                for (int ky = 0; ky < 3; ++ky)
                    #pragma unroll
                    for (int kx = 0; kx < 3; ++kx)
                        q += wc[ky*3+kx] * pr[ky][kx] + wc[9+ky*3+kx] * pv[ky][kx];
                m = fmaxf(m, q);
            }
            vn[1+y][1+x] = m;
            s += m;
            __syncthreads();
            float (*tmp)[34] = vc; vc = vn; vn = tmp;
        }
        sr1[1+y][1+x] = s * 0.25f;   // v1 overwrites r1 (safe after final barrier)
    }
    __syncthreads();

    // ---- P4+P5: m = upsample(v1), r = composite conv(X); rows gr0-1..gr0+32 ----
    {
        const float* WeffO = ws;
        const float* GO    = ws + 64;
        int c = t & 63;
        for (int ar = t >> 6; ar < 34; ar += 16) {
            int g = gr0 + ar - 1;
            if ((unsigned)g < 64u) {
                // bilinear upsample 32->64 at (g, c)
                int y0, y1; float wy0, wy1;
                if ((g & 1) == 0) { y1 = g >> 1; y0 = (y1 > 0) ? y1 - 1 : 0; wy1 = 0.75f; wy0 = 0.25f; }
                else              { y0 = g >> 1; y1 = (y0 < 31) ? y0 + 1 : 31; wy0 = 0.75f; wy1 = 0.25f; }
                int xa, xb; float wx0, wx1;
                if ((c & 1) == 0) { xb = c >> 1; xa = (xb > 0) ? xb - 1 : 0; wx1 = 0.75f; wx0 = 0.25f; }
                else              { xa = c >> 1; xb = (xa < 31) ? xa + 1 : 31; wx0 = 0.75f; wx1 = 0.25f; }
                sm[ar][1+c] = wy0 * (wx0 * sr1[1+y0][1+xa] + wx1 * sr1[1+y0][1+xb])
                            + wy1 * (wx0 * sr1[1+y1][1+xa] + wx1 * sr1[1+y1][1+xb]);
                // composite 5x5 conv of X at (g, c)
                float acc = 0.f;
                for (int i = 0; i < 2; ++i)
                    for (int oy = 0; oy < 5; ++oy) {
                        int yy = g + oy - 2; if (yy < 0 || yy >= 64) continue;
                        for (int ox = 0; ox < 5; ++ox) {
                            int xx = c + ox - 2; if (xx < 0 || xx >= 64) continue;
                            acc += WeffO[i*25 + oy*5 + ox] * sX[i][yy][xx];
                        }
                    }
                if (g == 0 || g == 63 || c == 0 || c == 63) {
                    float corr = 0.f;
                    for (int by = 0; by < 3; ++by)
                        for (int bx = 0; bx < 3; ++bx) {
                            int qy = g + by - 1, qx = c + bx - 1;
                            if (qy >= 0 && qy < 64 && qx >= 0 && qx < 64) continue;
                            const float* Gb = GO + (by*3+bx)*18;
                            for (int i = 0; i < 2; ++i)
                                for (int ay = 0; ay < 3; ++ay) {
                                    int yy2 = qy + ay - 1; if (yy2 < 0 || yy2 >= 64) continue;
                                    for (int ax = 0; ax < 3; ++ax) {
                                        int xx2 = qx + ax - 1; if (xx2 < 0 || xx2 >= 64) continue;
                                        corr += Gb[i*9 + ay*3 + ax] * sX[i][yy2][xx2];
                                    }
                                }
                        }
                    acc -= corr;
                }
                sr[ar][1+c] = acc;
            }
        }
    }
    __syncthreads();

    // ---- P6: outer VI loop, own 32 rows; per-step halo exchange with pair ----
    const int rp = t >> 6;          // 0..15 -> own local rows {2rp, 2rp+1}
    const int c  = t & 63;
    const int sendRp  = half ? 0 : 15;   // row that borders the partner
    const int recvRow = half ? 0 : 33;   // array row holding partner halo

    float pm[4][3], prr[4][3];
    #pragma unroll
    for (int dy = 0; dy < 4; ++dy)
        #pragma unroll
        for (int dx = 0; dx < 3; ++dx) {
            pm[dy][dx]  = sm[2*rp+dy][c+dx];
            prr[dy][dx] = sr[2*rp+dy][c+dx];
        }

    float s0 = 0.f, s1 = 0.f;
    float (*Vc)[66] = sV[0];
    float (*Vn)[66] = sV[1];

    for (int k = 0; k < 16; ++k) {
        const float* wk = conv_q_ws + k * 270;
        float pv[4][3];
        #pragma unroll
        for (int dy = 0; dy < 4; ++dy)
            #pragma unroll
            for (int dx = 0; dx < 3; ++dx)
                pv[dy][dx] = Vc[2*rp+dy][c+dx];
        float vm0 = NEG_BIG, vm1 = NEG_BIG;
        for (int ch = 0; ch < 10; ++ch) {
            const float* wc = wk + ch * 27;
            float q0 = 0.f, q1 = 0.f;
            #pragma unroll
            for (int ky = 0; ky < 3; ++ky)
                #pragma unroll
                for (int kx = 0; kx < 3; ++kx) {
                    float wm = wc[ky*3+kx];
                    float wr = wc[9  + ky*3+kx];
                    float wv = wc[18 + ky*3+kx];
                    q0 += wm * pm[ky][kx]   + wr * prr[ky][kx]   + wv * pv[ky][kx];
                    q1 += wm * pm[ky+1][kx] + wr * prr[ky+1][kx] + wv * pv[ky+1][kx];
                }
            vm0 = fmaxf(vm0, q0);
            vm1 = fmaxf(vm1, q1);
        }
        Vn[1+2*rp][1+c] = vm0;
        Vn[2+2*rp][1+c] = vm1;
        s0 += vm0;
        s1 += vm1;
        if (k < 15) {
            if (rp == sendRp)
                __hip_atomic_store(ghMine + (k&1)*64 + c, half ? vm0 : vm1,
                                   __ATOMIC_RELAXED, SCOPE_AGENT);
            __syncthreads();   // drains vmcnt for all waves -> sends visible
            if (t < 64) {
                if (t == 0) {
                    __hip_atomic_store(flagMine, k+1, __ATOMIC_RELEASE, SCOPE_AGENT);
                    int spins = 0;
                    while (__hip_atomic_load(flagPart, __ATOMIC_ACQUIRE, SCOPE_AGENT) < k+1) {
                        if (++spins > (1 << 27)) break;   // safety valve: no hang
                    }
                }
                float hv = __hip_atomic_load(ghPart + (k&1)*64 + t,
                                             __ATOMIC_RELAXED, SCOPE_AGENT);
                Vn[recvRow][1+t] = hv;
            }
            __syncthreads();
        } else {
            __syncthreads();
        }
        float (*tmp)[66] = Vc; Vc = Vn; Vn = tmp;
    }

    // ---- vbar = sum/16 into Vn (= old v14 buffer), exchange its halo ----
    float vb0 = s0 * 0.0625f, vb1 = s1 * 0.0625f;
    Vn[1+2*rp][1+c] = vb0;
    Vn[2+2*rp][1+c] = vb1;
    if (rp == sendRp)
        __hip_atomic_store(ghMine + 64 + c, half ? vb0 : vb1,
                           __ATOMIC_RELAXED, SCOPE_AGENT);
    __syncthreads();
    if (t >= 64 && t < 84) ((float*)sRed)[t - 64] = 0.f;
    if (t < 64) {
        if (t == 0) {
            __hip_atomic_store(flagMine, 16, __ATOMIC_RELEASE, SCOPE_AGENT);
            int spins = 0;
            while (__hip_atomic_load(flagPart, __ATOMIC_ACQUIRE, SCOPE_AGENT) < 16) {
                if (++spins > (1 << 27)) break;
            }
        }
        float hv = __hip_atomic_load(ghPart + 64 + t, __ATOMIC_RELAXED, SCOPE_AGENT);
        Vn[recvRow][1+t] = hv;
    }
    __syncthreads();

    // ---- P7: final conv (w15) on {m, r, vbar} + BN stats + (S1,S2) pick ----
    {
        const float* wk = conv_q_ws + 15 * 270;
        float pv[4][3];
        #pragma unroll
        for (int dy = 0; dy < 4; ++dy)
            #pragma unroll
            for (int dx = 0; dx < 3; ++dx)
                pv[dy][dx] = Vn[2*rp+dy][c+dx];
        int sy = S1[n], sx = S2[n];
        int g0 = gr0 + 2*rp, g1 = g0 + 1;
        float* qpix = wsm + 544 + n * 10;
        for (int ch = 0; ch < 10; ++ch) {
            const float* wc = wk + ch * 27;
            float q0 = 0.f, q1 = 0.f;
            #pragma unroll
            for (int ky = 0; ky < 3; ++ky)
                #pragma unroll
                for (int kx = 0; kx < 3; ++kx) {
                    float wm = wc[ky*3+kx];
                    float wr = wc[9  + ky*3+kx];
                    float wv = wc[18 + ky*3+kx];
                    q0 += wm * pm[ky][kx]   + wr * prr[ky][kx]   + wv * pv[ky][kx];
                    q1 += wm * pm[ky+1][kx] + wr * prr[ky+1][kx] + wv * pv[ky+1][kx];
                }
            if (c == sx) {
                if (g0 == sy) qpix[ch] = q0;
                if (g1 == sy) qpix[ch] = q1;
            }
            float ls = q0 + q1, lq = q0*q0 + q1*q1;
            #pragma unroll
            for (int off = 32; off > 0; off >>= 1) {
                ls += __shfl_down(ls, off);
                lq += __shfl_down(lq, off);
            }
            if ((t & 63) == 0) {
                atomicAdd(&sRed[ch][0], ls);
                atomicAdd(&sRed[ch][1], lq);
            }
        }
        __syncthreads();
        if (t < 10) {
            atomicAdd(wsm + 512 + t, sRed[t][0]);
            atomicAdd(wsm + 528 + t, sRed[t][1]);
        }
    }
}

__global__ void k_final(const float* __restrict__ ws,
                        const float* __restrict__ gamma,
                        const float* __restrict__ beta,
                        const float* __restrict__ w1,
                        const float* __restrict__ w2,
                        float* __restrict__ out) {
    int n = threadIdx.x;
    if (n >= 128) return;
    const float inv = 1.f / 524288.f;
    float qn[10];
    for (int c = 0; c < 10; ++c) {
        float mean = ws[512 + c] * inv;
        float var  = ws[528 + c] * inv - mean * mean;
        float q    = ws[544 + n * 10 + c];
        qn[c] = (q - mean) * rsqrtf(var + 1e-5f) * gamma[c] + beta[c];
    }
    float a = 0.f;
    for (int c = 0; c < 10; ++c) a += qn[c] * w1[c];
    a = fmaxf(a, 0.f);
    float b[8], mb = 0.f;
    for (int j = 0; j < 8; ++j) {
        float bj = 0.f;
        for (int c = 0; c < 10; ++c) bj += qn[c] * w2[j * 10 + c];
        bj = fmaxf(bj, 0.f);
        b[j] = bj;
        mb += bj;
    }
    mb *= 0.125f;
    for (int j = 0; j < 8; ++j) out[n * 8 + j] = a + b[j] - mb;
}

extern "C" void kernel_launch(void* const* d_in, const int* in_sizes, int n_in,
                              void* d_out, int out_size, void* d_ws, size_t ws_size,
                              hipStream_t stream) {
    const float* X         = (const float*)d_in[0];
    const int*   S1        = (const int*)  d_in[1];
    const int*   S2        = (const int*)  d_in[2];
    const float* conv_h_w  = (const float*)d_in[3];
    const float* conv_r_w  = (const float*)d_in[4];
    const float* conv_q_ws = (const float*)d_in[5];
    const float* bn_gamma  = (const float*)d_in[6];
    const float* bn_beta   = (const float*)d_in[7];
    const float* duel_w1   = (const float*)d_in[8];
    const float* duel_w2   = (const float*)d_in[9];
    const float* vi_h_w    = (const float*)d_in[10];
    const float* vi_r_w    = (const float*)d_in[11];
    const float* vi_q_ws   = (const float*)d_in[12];
    float* ws = (float*)d_ws;

    k_precomp<<<1, 512, 0, stream>>>(conv_h_w, conv_r_w, vi_h_w, vi_r_w, ws);
    k_main<<<256, 1024, 0, stream>>>(X, S1, S2, conv_q_ws, vi_q_ws, ws, ws);
    k_final<<<1, 128, 0, stream>>>(ws, bn_gamma, bn_beta, duel_w1, duel_w2, (float*)d_out);
}